// Round 4
// baseline (494.568 us; speedup 1.0000x reference)
//
#include <hip/hip_runtime.h>
#include <hip/hip_bf16.h>
#include <cstdint>

#define B_ 32
#define S_ 4096
#define H_ 512

typedef _Float16 f16x8 __attribute__((ext_vector_type(8)));
typedef _Float16 f16x4 __attribute__((ext_vector_type(4)));
typedef float    f32x4 __attribute__((ext_vector_type(4)));

// global_load_lds, 16B/lane: LDS dst must be linear (wave-uniform base + lane*16)
#define GLDS16(gsrc, ldst) \
    __builtin_amdgcn_global_load_lds((const __attribute__((address_space(1))) void*)(gsrc), \
        (__attribute__((address_space(3))) void*)(ldst), 16, 0, 0)

__device__ __forceinline__ float tanh_fast(float x) {
    float e = __expf(2.0f * x);
    return 1.0f - 2.0f / (e + 1.0f);
}

// ---------------- prep: q = query @ Wq^T  (fp32, tiny) ----------------
// 256 blocks: b = blk>>3, 64 rows each; 4 threads per row, shfl-reduce.
__global__ void prep_q(const float* __restrict__ query,
                       const float* __restrict__ Wq,
                       float* __restrict__ q_ws) {
    int blk = blockIdx.x;
    int b   = blk >> 3;
    int r0  = (blk & 7) * 64;
    int t   = threadIdx.x;            // 256
    __shared__ float qs[H_];
    qs[t]       = query[b * H_ + t];
    qs[t + 256] = query[b * H_ + t + 256];
    __syncthreads();
    int row  = r0 + (t >> 2);
    int part = t & 3;
    const float4* wrow = (const float4*)(Wq + (size_t)row * H_) + part * 32;
    const float*  qsp  = qs + part * 128;
    float acc = 0.f;
    #pragma unroll 8
    for (int j = 0; j < 32; ++j) {
        float4 w = wrow[j];
        acc += qsp[j*4+0]*w.x + qsp[j*4+1]*w.y + qsp[j*4+2]*w.z + qsp[j*4+3]*w.w;
    }
    acc += __shfl_xor(acc, 1);
    acc += __shfl_xor(acc, 2);
    if (part == 0) q_ws[b * H_ + row] = acc;
}

// ------- prep: Wk fp32 -> fp16, pre-swizzled per-K-step tile layout -------
// wk16[ks][i][chunk_swz]: ks=0..15, i=0..511, 4 chunks x 8 halfs; swz = c ^ ((i>>1)&3)
__global__ void prep_wk(const float* __restrict__ Wk, _Float16* __restrict__ wk16) {
    int tid = blockIdx.x * 256 + threadIdx.x;   // 0..32767
    int c  = tid & 3;
    int i  = (tid >> 2) & 511;
    int ks = tid >> 11;
    const float* src = Wk + (size_t)i * H_ + ks * 32 + c * 8;
    float4 a = *(const float4*)(src);
    float4 d = *(const float4*)(src + 4);
    f16x8 p;
    p[0] = (_Float16)a.x; p[1] = (_Float16)a.y; p[2] = (_Float16)a.z; p[3] = (_Float16)a.w;
    p[4] = (_Float16)d.x; p[5] = (_Float16)d.y; p[6] = (_Float16)d.z; p[7] = (_Float16)d.w;
    int swz = c ^ ((i >> 1) & 3);
    *(f16x8*)(wk16 + (size_t)ks * 16384 + i * 32 + swz * 8) = p;
}

// ------------- scores[bs] = sum_i tanh(q[b,i] + (keys@Wk^T)[bs,i]) * v[i] -------------
// 64 rows x 512 cols per block, 4 waves (each 64x128). 2-phase pipeline, dbuf LDS,
// B staged via global_load_lds (pre-swizzled linear), A reg-staged fp32->fp16.
__global__ __launch_bounds__(256, 2) void scores_kernel(
        const float* __restrict__ keys, const _Float16* __restrict__ wk16,
        const float* __restrict__ q_ws, const float* __restrict__ v,
        float* __restrict__ scores) {
    __shared__ __align__(16) _Float16 As[2][64 * 32];    // 2 x 4 KB
    __shared__ __align__(16) _Float16 Bs[2][512 * 32];   // 2 x 32 KB
    __shared__ float srow[4][64];

    int t    = threadIdx.x;
    int lane = t & 63;
    int wid  = t >> 6;
    int m0   = blockIdx.x * 64;
    int b    = m0 >> 12;
    const float* akeys = keys + (size_t)m0 * H_;

    f32x4 acc[4][8] = {};

    // A-staging geometry (fixed per thread): two rows, idx = t and t+256
    int arow0 = t >> 3, ac4 = t & 7;           // arow0 0..31
    int arow1 = arow0 + 32;
    int aswz0 = (ac4 >> 1) ^ ((arow0 >> 1) & 3);
    int aswz1 = (ac4 >> 1) ^ ((arow1 >> 1) & 3);

    // ---- prologue: stage ks=0 into buffer 0 ----
    {
        const _Float16* bsrc = wk16;
        #pragma unroll
        for (int j = 0; j < 8; ++j)
            GLDS16(bsrc + (j * 256 + t) * 8, &Bs[0][(j * 256 + t) * 8]);
        float4 kv0 = *(const float4*)(akeys + (size_t)arow0 * H_ + ac4 * 4);
        float4 kv1 = *(const float4*)(akeys + (size_t)arow1 * H_ + ac4 * 4);
        f16x4 h0, h1;
        h0[0] = (_Float16)kv0.x; h0[1] = (_Float16)kv0.y; h0[2] = (_Float16)kv0.z; h0[3] = (_Float16)kv0.w;
        h1[0] = (_Float16)kv1.x; h1[1] = (_Float16)kv1.y; h1[2] = (_Float16)kv1.z; h1[3] = (_Float16)kv1.w;
        *(f16x4*)&As[0][arow0 * 32 + aswz0 * 8 + (ac4 & 1) * 4] = h0;
        *(f16x4*)&As[0][arow1 * 32 + aswz1 * 8 + (ac4 & 1) * 4] = h1;
    }
    __syncthreads();   // implies vmcnt(0)+lgkmcnt(0): glds + writes complete

    int cur = 0;
    for (int ks = 0; ks < 16; ++ks) {
        int nb = cur ^ 1;
        float4 kv0, kv1;
        // ---- issue next-tile STAGE first (loads fly under MFMA) ----
        if (ks < 15) {
            const _Float16* bsrc = wk16 + (size_t)(ks + 1) * 16384;
            #pragma unroll
            for (int j = 0; j < 8; ++j)
                GLDS16(bsrc + (j * 256 + t) * 8, &Bs[nb][(j * 256 + t) * 8]);
            kv0 = *(const float4*)(akeys + (size_t)arow0 * H_ + (ks + 1) * 32 + ac4 * 4);
            kv1 = *(const float4*)(akeys + (size_t)arow1 * H_ + (ks + 1) * 32 + ac4 * 4);
        }
        // ---- fragments from current buffer ----
        int chunk = lane >> 4;
        f16x8 af[4];
        #pragma unroll
        for (int mf = 0; mf < 4; ++mf) {
            int row = mf * 16 + (lane & 15);
            af[mf] = *(const f16x8*)&As[cur][row * 32 + (chunk ^ ((row >> 1) & 3)) * 8];
        }
        f16x8 bf[8];
        #pragma unroll
        for (int nf = 0; nf < 8; ++nf) {
            int row = wid * 128 + nf * 16 + (lane & 15);
            bf[nf] = *(const f16x8*)&Bs[cur][row * 32 + (chunk ^ ((row >> 1) & 3)) * 8];
        }
        #pragma unroll
        for (int mf = 0; mf < 4; ++mf)
            #pragma unroll
            for (int nf = 0; nf < 8; ++nf)
                acc[mf][nf] = __builtin_amdgcn_mfma_f32_16x16x32_f16(af[mf], bf[nf], acc[mf][nf], 0, 0, 0);
        // ---- convert+write A for next tile (after MFMA: loads had time to land) ----
        if (ks < 15) {
            f16x4 h0, h1;
            h0[0] = (_Float16)kv0.x; h0[1] = (_Float16)kv0.y; h0[2] = (_Float16)kv0.z; h0[3] = (_Float16)kv0.w;
            h1[0] = (_Float16)kv1.x; h1[1] = (_Float16)kv1.y; h1[2] = (_Float16)kv1.z; h1[3] = (_Float16)kv1.w;
            *(f16x4*)&As[nb][arow0 * 32 + aswz0 * 8 + (ac4 & 1) * 4] = h0;
            *(f16x4*)&As[nb][arow1 * 32 + aswz1 * 8 + (ac4 & 1) * 4] = h1;
        }
        __syncthreads();   // drains glds (vmcnt) + LDS writes; one barrier per iter
        cur = nb;
    }

    // ---- epilogue: rowsum of tanh(q + k) * v ----
    float qv[8], vv[8];
    #pragma unroll
    for (int nf = 0; nf < 8; ++nf) {
        int col = wid * 128 + nf * 16 + (lane & 15);
        qv[nf] = q_ws[b * H_ + col];
        vv[nf] = v[col];
    }
    #pragma unroll
    for (int mf = 0; mf < 4; ++mf) {
        f32x4 rs = {0.f, 0.f, 0.f, 0.f};
        #pragma unroll
        for (int nf = 0; nf < 8; ++nf)
            #pragma unroll
            for (int r = 0; r < 4; ++r)
                rs[r] += tanh_fast(qv[nf] + acc[mf][nf][r]) * vv[nf];
        #pragma unroll
        for (int off = 1; off < 16; off <<= 1)
            #pragma unroll
            for (int r = 0; r < 4; ++r)
                rs[r] += __shfl_xor(rs[r], off);
        if ((lane & 15) == 0) {
            #pragma unroll
            for (int r = 0; r < 4; ++r)
                srow[wid][mf * 16 + (lane >> 4) * 4 + r] = rs[r];
        }
    }
    __syncthreads();
    if (t < 64)
        scores[m0 + t] = srow[0][t] + srow[1][t] + srow[2][t] + srow[3][t];
}

// ---------------- softmax over S with mask (int32) ----------------
__global__ void softmax_kernel(const float* __restrict__ scores,
                               const int* __restrict__ mask,
                               float* __restrict__ attn) {
    int b = blockIdx.x, t = threadIdx.x;   // 256 threads
    __shared__ float red[8];
    float x[16];
    float m = -1e30f;
    #pragma unroll
    for (int j = 0; j < 16; ++j) {
        int s = t + j * 256;
        float sc = scores[b * S_ + s];
        x[j] = (mask[b * S_ + s] != 0) ? sc : -1e9f;
        m = fmaxf(m, x[j]);
    }
    #pragma unroll
    for (int off = 1; off < 64; off <<= 1) m = fmaxf(m, __shfl_xor(m, off));
    if ((t & 63) == 0) red[t >> 6] = m;
    __syncthreads();
    m = fmaxf(fmaxf(red[0], red[1]), fmaxf(red[2], red[3]));
    float sum = 0.f;
    #pragma unroll
    for (int j = 0; j < 16; ++j) { x[j] = __expf(x[j] - m); sum += x[j]; }
    #pragma unroll
    for (int off = 1; off < 64; off <<= 1) sum += __shfl_xor(sum, off);
    if ((t & 63) == 0) red[4 + (t >> 6)] = sum;
    __syncthreads();
    float inv = 1.0f / (red[4] + red[5] + red[6] + red[7]);
    #pragma unroll
    for (int j = 0; j < 16; ++j)
        attn[b * S_ + t + j * 256] = x[j] * inv;
}

// ---------------- ctx = attn @ keys  (memory-bound) ----------------
__global__ void ctx_kernel(const float* __restrict__ keys,
                           const float* __restrict__ attn,
                           float* __restrict__ ctx) {
    int blk = blockIdx.x;
    int b = blk >> 4, c = blk & 15;
    int s0 = c * 256;
    int t = threadIdx.x;   // 256
    __shared__ float attn_s[256];
    __shared__ float ctx_l[512];
    attn_s[t] = attn[b * S_ + s0 + t];
    __syncthreads();
    int h4 = t & 127, sp = t >> 7;
    f32x4 acc = {0.f, 0.f, 0.f, 0.f};
    const float4* kb = (const float4*)(keys + ((size_t)b * S_ + s0) * H_);
    for (int it = 0; it < 128; ++it) {
        int srow = it * 2 + sp;
        float a = attn_s[srow];
        float4 kv = kb[(size_t)srow * 128 + h4];
        acc[0] += a * kv.x; acc[1] += a * kv.y; acc[2] += a * kv.z; acc[3] += a * kv.w;
    }
    if (sp == 0) {
        #pragma unroll
        for (int r = 0; r < 4; ++r) ctx_l[h4 * 4 + r] = acc[r];
    }
    __syncthreads();
    if (sp == 1) {
        #pragma unroll
        for (int r = 0; r < 4; ++r) ctx_l[h4 * 4 + r] += acc[r];
    }
    __syncthreads();
    atomicAdd(&ctx[b * H_ + t], ctx_l[t]);
    atomicAdd(&ctx[b * H_ + t + 256], ctx_l[t + 256]);
}

extern "C" void kernel_launch(void* const* d_in, const int* in_sizes, int n_in,
                              void* d_out, int out_size, void* d_ws, size_t ws_size,
                              hipStream_t stream) {
    const float* query = (const float*)d_in[0];
    const float* keys  = (const float*)d_in[1];
    const int*   mask  = (const int*)d_in[2];   // jnp bool uploads as int32
    const float* Wq    = (const float*)d_in[3];
    const float* Wk    = (const float*)d_in[4];
    const float* v     = (const float*)d_in[5];

    float* out  = (float*)d_out;
    float* ctx  = out;             // [32*512]
    float* attn = out + B_ * H_;   // [32*4096]

    char* ws = (char*)d_ws;
    float*    q_ws   = (float*)ws;                          // 64 KB
    _Float16* wk16   = (_Float16*)(ws + 65536);             // 512 KB
    float*    scores = (float*)(ws + 65536 + 524288);       // 512 KB

    hipMemsetAsync(ctx, 0, B_ * H_ * sizeof(float), stream);
    prep_q<<<256, 256, 0, stream>>>(query, Wq, q_ws);
    prep_wk<<<128, 256, 0, stream>>>(Wk, wk16);
    scores_kernel<<<2048, 256, 0, stream>>>(keys, wk16, q_ws, v, scores);
    softmax_kernel<<<32, 256, 0, stream>>>(scores, mask, attn);
    ctx_kernel<<<512, 256, 0, stream>>>(keys, attn, ctx);
}

// Round 7
// 473.106 us; speedup vs baseline: 1.0454x; 1.0454x over previous
//
#include <hip/hip_runtime.h>
#include <hip/hip_bf16.h>
#include <cstdint>

#define B_ 32
#define S_ 4096
#define H_ 512

typedef _Float16 f16x8 __attribute__((ext_vector_type(8)));
typedef _Float16 f16x4 __attribute__((ext_vector_type(4)));
typedef float    f32x4 __attribute__((ext_vector_type(4)));

__device__ __forceinline__ float tanh_fast(float x) {
    float e = __expf(2.0f * x);
    return 1.0f - 2.0f / (e + 1.0f);
}

// ---------------- prep: q = query @ Wq^T  (fp32, tiny) ----------------
__global__ void prep_q(const float* __restrict__ query,
                       const float* __restrict__ Wq,
                       float* __restrict__ q_ws) {
    int blk = blockIdx.x;
    int b   = blk >> 3;
    int r0  = (blk & 7) * 64;
    int t   = threadIdx.x;            // 256
    __shared__ float qs[H_];
    qs[t]       = query[b * H_ + t];
    qs[t + 256] = query[b * H_ + t + 256];
    __syncthreads();
    int row  = r0 + (t >> 2);
    int part = t & 3;
    const float4* wrow = (const float4*)(Wq + (size_t)row * H_) + part * 32;
    const float*  qsp  = qs + part * 128;
    float acc = 0.f;
    #pragma unroll 8
    for (int j = 0; j < 32; ++j) {
        float4 w = wrow[j];
        acc += qsp[j*4+0]*w.x + qsp[j*4+1]*w.y + qsp[j*4+2]*w.z + qsp[j*4+3]*w.w;
    }
    acc += __shfl_xor(acc, 1);
    acc += __shfl_xor(acc, 2);
    if (part == 0) q_ws[b * H_ + row] = acc;
}

// ------- prep: Wk fp32 -> fp16, fragment-block layout for direct-to-reg B loads -------
// fb = ks*32 + nfg  (nfg = B-row block of 16). Block fb holds 16 rows x 32 k, stored so
// lane l's 16B = row nfg*16+(l&15), k = ks*32+(l>>4)*8 .. +7  ->  wk16[fb*512 + l*8]
__global__ void prep_wk(const float* __restrict__ Wk, _Float16* __restrict__ wk16) {
    int tid  = blockIdx.x * 256 + threadIdx.x;   // 0..32767
    int lane = tid & 63;
    int fb   = tid >> 6;          // 0..511
    int ks   = fb >> 5;
    int nfg  = fb & 31;
    int i    = nfg * 16 + (lane & 15);        // B-row
    int k0   = ks * 32 + (lane >> 4) * 8;     // first of 8 k
    const float* src = Wk + (size_t)i * H_ + k0;
    float4 a = *(const float4*)(src);
    float4 d = *(const float4*)(src + 4);
    f16x8 p;
    p[0] = (_Float16)a.x; p[1] = (_Float16)a.y; p[2] = (_Float16)a.z; p[3] = (_Float16)a.w;
    p[4] = (_Float16)d.x; p[5] = (_Float16)d.y; p[6] = (_Float16)d.z; p[7] = (_Float16)d.w;
    *(f16x8*)(wk16 + (size_t)fb * 512 + lane * 8) = p;
}

// ------------- scores[bs] = sum_i tanh(q[b,i] + (keys@Wk^T)[bs,i]) * v[i] -------------
// 64 rows x 512 cols per block, 4 waves (each 64x128).
// B: direct global->reg from L2-resident wk16, prefetch dist 1 (no LDS, no vmcnt coupling).
// A: reg-staged fp32->fp16 into 2x4KB LDS, prefetch dist 2.
// Barrier: raw s_barrier + lgkmcnt(0) only -- vmem loads stay in flight across it.
__global__ __launch_bounds__(256, 2) void scores_kernel(
        const float* __restrict__ keys, const _Float16* __restrict__ wk16,
        const float* __restrict__ q_ws, const float* __restrict__ v,
        float* __restrict__ scores) {
    __shared__ __align__(16) _Float16 As[2][64 * 32];    // 2 x 4 KB
    __shared__ float srow[4][64];

    int t    = threadIdx.x;
    int lane = t & 63;
    int wid  = t >> 6;
    int m0   = blockIdx.x * 64;
    int b    = m0 >> 12;
    const float* akeys = keys + (size_t)m0 * H_;

    f32x4 acc[4][8] = {};

    // A-staging geometry (fixed per thread): two rows, idx = t and t+256
    int arow0 = t >> 3, ac4 = t & 7;
    int arow1 = arow0 + 32;
    int aswz0 = (ac4 >> 1) ^ ((arow0 >> 1) & 3);
    int aswz1 = (ac4 >> 1) ^ ((arow1 >> 1) & 3);
    _Float16* aw0[2] = { &As[0][arow0 * 32 + aswz0 * 8 + (ac4 & 1) * 4],
                         &As[1][arow0 * 32 + aswz0 * 8 + (ac4 & 1) * 4] };
    _Float16* aw1[2] = { &As[0][arow1 * 32 + aswz1 * 8 + (ac4 & 1) * 4],
                         &As[1][arow1 * 32 + aswz1 * 8 + (ac4 & 1) * 4] };

    // B base: lane-coalesced fragment blocks
    const _Float16* bptr = wk16 + (size_t)(wid * 8) * 512 + lane * 8;

    f16x8  bf[2][8];
    float4 kvp[2][2];   // kvp[p] holds keys rows for K-step of parity p

    // ---- prologue ----
    {
        #pragma unroll
        for (int nf = 0; nf < 8; ++nf)
            bf[0][nf] = *(const f16x8*)(bptr + nf * 512);
        float4 a0 = *(const float4*)(akeys + (size_t)arow0 * H_ + ac4 * 4);
        float4 a1 = *(const float4*)(akeys + (size_t)arow1 * H_ + ac4 * 4);
        kvp[1][0] = *(const float4*)(akeys + (size_t)arow0 * H_ + 32 + ac4 * 4);
        kvp[1][1] = *(const float4*)(akeys + (size_t)arow1 * H_ + 32 + ac4 * 4);
        f16x4 h0, h1;
        h0[0] = (_Float16)a0.x; h0[1] = (_Float16)a0.y; h0[2] = (_Float16)a0.z; h0[3] = (_Float16)a0.w;
        h1[0] = (_Float16)a1.x; h1[1] = (_Float16)a1.y; h1[2] = (_Float16)a1.z; h1[3] = (_Float16)a1.w;
        *(f16x4*)aw0[0] = h0;
        *(f16x4*)aw1[0] = h1;
    }
    asm volatile("s_waitcnt lgkmcnt(0)\n\ts_barrier" ::: "memory");

    #pragma unroll
    for (int ks = 0; ks < 16; ++ks) {
        // prefetch A for ks+2 (dist 2; parity (ks+2)&1 == ks&1)
        if (ks < 14) {
            kvp[ks & 1][0] = *(const float4*)(akeys + (size_t)arow0 * H_ + (ks + 2) * 32 + ac4 * 4);
            kvp[ks & 1][1] = *(const float4*)(akeys + (size_t)arow1 * H_ + (ks + 2) * 32 + ac4 * 4);
        }
        // prefetch B for ks+1 (dist 1)
        if (ks < 15) {
            #pragma unroll
            for (int nf = 0; nf < 8; ++nf)
                bf[(ks + 1) & 1][nf] = *(const f16x8*)(bptr + (size_t)(ks + 1) * 16384 + nf * 512);
        }
        // A fragments from LDS
        int chunk = lane >> 4;
        f16x8 af[4];
        #pragma unroll
        for (int mf = 0; mf < 4; ++mf) {
            int row = mf * 16 + (lane & 15);
            af[mf] = *(const f16x8*)&As[ks & 1][row * 32 + (chunk ^ ((row >> 1) & 3)) * 8];
        }
        #pragma unroll
        for (int mf = 0; mf < 4; ++mf)
            #pragma unroll
            for (int nf = 0; nf < 8; ++nf)
                acc[mf][nf] = __builtin_amdgcn_mfma_f32_16x16x32_f16(af[mf], bf[ks & 1][nf], acc[mf][nf], 0, 0, 0);
        // convert + write A for ks+1 (loaded 2 iters ago)
        if (ks < 15) {
            float4 k0 = kvp[(ks + 1) & 1][0], k1 = kvp[(ks + 1) & 1][1];
            f16x4 h0, h1;
            h0[0] = (_Float16)k0.x; h0[1] = (_Float16)k0.y; h0[2] = (_Float16)k0.z; h0[3] = (_Float16)k0.w;
            h1[0] = (_Float16)k1.x; h1[1] = (_Float16)k1.y; h1[2] = (_Float16)k1.z; h1[3] = (_Float16)k1.w;
            *(f16x4*)aw0[(ks + 1) & 1] = h0;
            *(f16x4*)aw1[(ks + 1) & 1] = h1;
        }
        asm volatile("s_waitcnt lgkmcnt(0)\n\ts_barrier" ::: "memory");
    }

    // ---- epilogue: rowsum of tanh(q + k) * v ----
    float qv[8], vv[8];
    #pragma unroll
    for (int nf = 0; nf < 8; ++nf) {
        int col = wid * 128 + nf * 16 + (lane & 15);
        qv[nf] = q_ws[b * H_ + col];
        vv[nf] = v[col];
    }
    #pragma unroll
    for (int mf = 0; mf < 4; ++mf) {
        f32x4 rs = {0.f, 0.f, 0.f, 0.f};
        #pragma unroll
        for (int nf = 0; nf < 8; ++nf)
            #pragma unroll
            for (int r = 0; r < 4; ++r)
                rs[r] += tanh_fast(qv[nf] + acc[mf][nf][r]) * vv[nf];
        #pragma unroll
        for (int off = 1; off < 16; off <<= 1)
            #pragma unroll
            for (int r = 0; r < 4; ++r)
                rs[r] += __shfl_xor(rs[r], off);
        if ((lane & 15) == 0) {
            #pragma unroll
            for (int r = 0; r < 4; ++r)
                srow[wid][mf * 16 + (lane >> 4) * 4 + r] = rs[r];
        }
    }
    __syncthreads();
    if (t < 64)
        scores[m0 + t] = srow[0][t] + srow[1][t] + srow[2][t] + srow[3][t];
}

// ---------------- softmax over S with mask (int32) ----------------
__global__ void softmax_kernel(const float* __restrict__ scores,
                               const int* __restrict__ mask,
                               float* __restrict__ attn) {
    int b = blockIdx.x, t = threadIdx.x;   // 256 threads
    __shared__ float red[8];
    float x[16];
    float m = -1e30f;
    #pragma unroll
    for (int j = 0; j < 16; ++j) {
        int s = t + j * 256;
        float sc = scores[b * S_ + s];
        x[j] = (mask[b * S_ + s] != 0) ? sc : -1e9f;
        m = fmaxf(m, x[j]);
    }
    #pragma unroll
    for (int off = 1; off < 64; off <<= 1) m = fmaxf(m, __shfl_xor(m, off));
    if ((t & 63) == 0) red[t >> 6] = m;
    __syncthreads();
    m = fmaxf(fmaxf(red[0], red[1]), fmaxf(red[2], red[3]));
    float sum = 0.f;
    #pragma unroll
    for (int j = 0; j < 16; ++j) { x[j] = __expf(x[j] - m); sum += x[j]; }
    #pragma unroll
    for (int off = 1; off < 64; off <<= 1) sum += __shfl_xor(sum, off);
    if ((t & 63) == 0) red[4 + (t >> 6)] = sum;
    __syncthreads();
    float inv = 1.0f / (red[4] + red[5] + red[6] + red[7]);
    #pragma unroll
    for (int j = 0; j < 16; ++j)
        attn[b * S_ + t + j * 256] = x[j] * inv;
}

// ---------------- ctx = attn @ keys  (memory-bound) ----------------
__global__ void ctx_kernel(const float* __restrict__ keys,
                           const float* __restrict__ attn,
                           float* __restrict__ ctx) {
    int blk = blockIdx.x;
    int b = blk >> 4, c = blk & 15;
    int s0 = c * 256;
    int t = threadIdx.x;   // 256
    __shared__ float attn_s[256];
    __shared__ float ctx_l[512];
    attn_s[t] = attn[b * S_ + s0 + t];
    __syncthreads();
    int h4 = t & 127, sp = t >> 7;
    f32x4 acc = {0.f, 0.f, 0.f, 0.f};
    const float4* kb = (const float4*)(keys + ((size_t)b * S_ + s0) * H_);
    for (int it = 0; it < 128; ++it) {
        int srow = it * 2 + sp;
        float a = attn_s[srow];
        float4 kv = kb[(size_t)srow * 128 + h4];
        acc[0] += a * kv.x; acc[1] += a * kv.y; acc[2] += a * kv.z; acc[3] += a * kv.w;
    }
    if (sp == 0) {
        #pragma unroll
        for (int r = 0; r < 4; ++r) ctx_l[h4 * 4 + r] = acc[r];
    }
    __syncthreads();
    if (sp == 1) {
        #pragma unroll
        for (int r = 0; r < 4; ++r) ctx_l[h4 * 4 + r] += acc[r];
    }
    __syncthreads();
    atomicAdd(&ctx[b * H_ + t], ctx_l[t]);
    atomicAdd(&ctx[b * H_ + t + 256], ctx_l[t + 256]);
}

extern "C" void kernel_launch(void* const* d_in, const int* in_sizes, int n_in,
                              void* d_out, int out_size, void* d_ws, size_t ws_size,
                              hipStream_t stream) {
    const float* query = (const float*)d_in[0];
    const float* keys  = (const float*)d_in[1];
    const int*   mask  = (const int*)d_in[2];   // jnp bool uploads as int32
    const float* Wq    = (const float*)d_in[3];
    const float* Wk    = (const float*)d_in[4];
    const float* v     = (const float*)d_in[5];

    float* out  = (float*)d_out;
    float* ctx  = out;             // [32*512]
    float* attn = out + B_ * H_;   // [32*4096]

    char* ws = (char*)d_ws;
    float*    q_ws   = (float*)ws;                          // 64 KB
    _Float16* wk16   = (_Float16*)(ws + 65536);             // 512 KB
    float*    scores = (float*)(ws + 65536 + 524288);       // 512 KB

    hipMemsetAsync(ctx, 0, B_ * H_ * sizeof(float), stream);
    prep_q<<<256, 256, 0, stream>>>(query, Wq, q_ws);
    prep_wk<<<128, 256, 0, stream>>>(Wk, wk16);
    scores_kernel<<<2048, 256, 0, stream>>>(keys, wk16, q_ws, v, scores);
    softmax_kernel<<<32, 256, 0, stream>>>(scores, mask, attn);
    ctx_kernel<<<512, 256, 0, stream>>>(keys, attn, ctx);
}